// Round 2
// baseline (1401.327 us; speedup 1.0000x reference)
//
#include <hip/hip_runtime.h>

#define N_NODES 10000
#define N_EDGES 160000
#define DVAL    512
#define DEPTH   10

// ---------------- CSR build ----------------

__global__ void zero_int_kernel(int* p, int n) {
    int i = blockIdx.x * 256 + threadIdx.x;
    if (i < n) p[i] = 0;
}

__global__ void count_deg_kernel(const int* __restrict__ dst, int* __restrict__ deg, int n) {
    int i = blockIdx.x * 256 + threadIdx.x;
    if (i < n) atomicAdd(&deg[dst[i]], 1);
}

// single block, 1024 threads, exclusive scan of deg[10000] -> row_ptr[10001], copy to cursor
__global__ __launch_bounds__(1024) void scan_kernel(const int* __restrict__ deg,
                                                    int* __restrict__ row_ptr,
                                                    int* __restrict__ cursor) {
    __shared__ int sums[1024];
    const int tid = threadIdx.x;
    const int CH = 10;  // 10 * 1024 >= 10000
    int base = tid * CH;
    int local[CH];
    int s = 0;
#pragma unroll
    for (int i = 0; i < CH; i++) {
        int idx = base + i;
        int v = (idx < N_NODES) ? deg[idx] : 0;
        local[i] = s;  // exclusive within chunk
        s += v;
    }
    sums[tid] = s;
    __syncthreads();
    for (int off = 1; off < 1024; off <<= 1) {
        int v = (tid >= off) ? sums[tid - off] : 0;
        __syncthreads();
        sums[tid] += v;
        __syncthreads();
    }
    int chunk_base = (tid > 0) ? sums[tid - 1] : 0;
#pragma unroll
    for (int i = 0; i < CH; i++) {
        int idx = base + i;
        if (idx < N_NODES) {
            int v = chunk_base + local[i];
            row_ptr[idx] = v;
            cursor[idx] = v;
        }
    }
    if (tid == 1023) row_ptr[N_NODES] = sums[1023];
}

__global__ void fill_edges_kernel(const int* __restrict__ src, const int* __restrict__ dst,
                                  int* __restrict__ cursor, int* __restrict__ esrc, int n) {
    int i = blockIdx.x * 256 + threadIdx.x;
    if (i < n) {
        int p = atomicAdd(&cursor[dst[i]], 1);
        esrc[p] = src[i];
    }
}

// ---------------- layer kernels ----------------

// input aggregation: F_IN = 6 floats per node
__global__ __launch_bounds__(64) void aggregate6_kernel(const float* __restrict__ feat,
                                                        const int* __restrict__ row_ptr,
                                                        const int* __restrict__ esrc,
                                                        float* __restrict__ agg6) {
    int node = blockIdx.x;
    int l = threadIdx.x;
    if (l >= 6) return;
    int start = row_ptr[node], end = row_ptr[node + 1];
    float acc = 0.f;
    for (int e = start; e < end; e++) acc += feat[esrc[e] * 6 + l];
    agg6[node * 6 + l] = acc;
}

// x = relu(agg6 @ W_in + b_in)   [10000 x 512], K = 6
__global__ __launch_bounds__(256) void input_layer_kernel(const float* __restrict__ agg6,
                                                          const float* __restrict__ W_in,
                                                          const float* __restrict__ b_in,
                                                          float* __restrict__ x) {
    int node = blockIdx.x;
    int j = threadIdx.x;
    float a[6];
#pragma unroll
    for (int k = 0; k < 6; k++) a[k] = agg6[node * 6 + k];
#pragma unroll
    for (int r = 0; r < 2; r++) {
        int jj = j + r * 256;
        float s = b_in[jj];
#pragma unroll
        for (int k = 0; k < 6; k++) s += a[k] * W_in[k * 512 + jj];
        x[(size_t)node * 512 + jj] = fmaxf(s, 0.f);
    }
}

// agg[node, :] = sum over incoming edges of x[src, :]   (D=512)
__global__ __launch_bounds__(128) void aggregate512_kernel(const float* __restrict__ x,
                                                           const int* __restrict__ row_ptr,
                                                           const int* __restrict__ esrc,
                                                           float* __restrict__ agg) {
    int node = blockIdx.x;
    int col = threadIdx.x * 4;
    int start = row_ptr[node], end = row_ptr[node + 1];
    float4 acc = make_float4(0.f, 0.f, 0.f, 0.f);
    for (int e = start; e < end; e++) {
        int s = esrc[e];
        float4 v = *(const float4*)(x + (size_t)s * 512 + col);
        acc.x += v.x; acc.y += v.y; acc.z += v.z; acc.w += v.w;
    }
    *(float4*)(agg + (size_t)node * 512 + col) = acc;
}

// C[M,512] = A[M,512] @ W[512,512] + bias ; fp32 tiled
// BM=128, BN=64, BK=16; 256 threads; 8x4 outputs/thread (two 4-row blocks).
// LDS layouts padded so all accesses are <=2-way bank aliased (free on gfx950).
#define BM 128
#define BN 64
#define BK 16
#define LDA 132   // padded leading dim of As[k][row]
#define LDB 68    // padded leading dim of Bs[k][col]
__global__ __launch_bounds__(256) void gemm_bias_kernel(const float* __restrict__ A,
                                                        const float* __restrict__ W,
                                                        const float* __restrict__ bias,
                                                        float* __restrict__ C, int M) {
    __shared__ float As[BK * LDA];  // As[k][r] : k-major, transposed A tile
    __shared__ float Bs[BK * LDB];  // Bs[k][c]
    const int bm = blockIdx.x * BM;
    const int bn = blockIdx.y * BN;
    const int tid = threadIdx.x;
    const int tx = tid & 15;   // col group: cols tx*4..tx*4+3
    const int ty = tid >> 4;   // row group: rows ty*4..+3 and 64+ty*4..+3

    // A staging map: positions p in {tid, tid+256}; r = p>>2 (0..127), cg = p&3
    const int a_r0 = tid >> 2;
    const int a_cg = (tid & 3) * 4;
    // B staging map: row = tid>>4 (0..15), col4 = (tid&15)*4
    const int b_r = tid >> 4;
    const int b_c = (tid & 15) * 4;

    float acc[8][4];
#pragma unroll
    for (int i = 0; i < 8; i++)
#pragma unroll
        for (int j = 0; j < 4; j++) acc[i][j] = 0.f;

    for (int kb = 0; kb < 512; kb += BK) {
        // stage A tile (128 x 16), transposed into As[k][r]
#pragma unroll
        for (int h = 0; h < 2; h++) {
            int r = a_r0 + h * 64;
            int arow = bm + r;
            float4 av = make_float4(0.f, 0.f, 0.f, 0.f);
            if (arow < M) av = *(const float4*)(A + (size_t)arow * 512 + kb + a_cg);
            As[(a_cg + 0) * LDA + r] = av.x;
            As[(a_cg + 1) * LDA + r] = av.y;
            As[(a_cg + 2) * LDA + r] = av.z;
            As[(a_cg + 3) * LDA + r] = av.w;
        }
        // stage B tile (16 x 64)
        {
            float4 bv = *(const float4*)(W + (size_t)(kb + b_r) * 512 + bn + b_c);
            *(float4*)&Bs[b_r * LDB + b_c] = bv;
        }
        __syncthreads();
#pragma unroll
        for (int k = 0; k < BK; k++) {
            float4 a0 = *(const float4*)&As[k * LDA + ty * 4];
            float4 a1 = *(const float4*)&As[k * LDA + 64 + ty * 4];
            float4 b0 = *(const float4*)&Bs[k * LDB + tx * 4];
            float ai[8] = {a0.x, a0.y, a0.z, a0.w, a1.x, a1.y, a1.z, a1.w};
            float bj[4] = {b0.x, b0.y, b0.z, b0.w};
#pragma unroll
            for (int i = 0; i < 8; i++)
#pragma unroll
                for (int j = 0; j < 4; j++) acc[i][j] += ai[i] * bj[j];
        }
        __syncthreads();
    }

    // epilogue: bias + store
    float4 bv = *(const float4*)(bias + bn + tx * 4);
#pragma unroll
    for (int h = 0; h < 2; h++) {
#pragma unroll
        for (int i = 0; i < 4; i++) {
            int row = bm + h * 64 + ty * 4 + i;
            if (row >= M) continue;
            float* a = acc[h * 4 + i];
            float4 o = make_float4(a[0] + bv.x, a[1] + bv.y, a[2] + bv.z, a[3] + bv.w);
            *(float4*)(C + (size_t)row * 512 + bn + tx * 4) = o;
        }
    }
}

// out[node] = dot(x[node,:], W_out) + b_out   (one wave per node)
__global__ __launch_bounds__(256) void output_layer_kernel(const float* __restrict__ x,
                                                           const float* __restrict__ W_out,
                                                           const float* __restrict__ b_out,
                                                           float* __restrict__ out) {
    int wave = threadIdx.x >> 6;
    int lane = threadIdx.x & 63;
    int node = blockIdx.x * 4 + wave;
    if (node >= N_NODES) return;
    float s = 0.f;
#pragma unroll
    for (int r = 0; r < 8; r++) {
        int k = lane + r * 64;
        s += x[(size_t)node * 512 + k] * W_out[k];
    }
#pragma unroll
    for (int off = 32; off > 0; off >>= 1) s += __shfl_down(s, off, 64);
    if (lane == 0) out[node] = s + b_out[0];
}

// ---------------- launch ----------------

extern "C" void kernel_launch(void* const* d_in, const int* in_sizes, int n_in,
                              void* d_out, int out_size, void* d_ws, size_t ws_size,
                              hipStream_t stream) {
    const float* features = (const float*)d_in[0];  // [10000, 6]
    const float* W_in     = (const float*)d_in[1];  // [6, 512]
    const float* b_in     = (const float*)d_in[2];  // [512]
    const float* Ws       = (const float*)d_in[3];  // [10, 512, 512]
    const float* bs       = (const float*)d_in[4];  // [10, 512]
    const float* W_out    = (const float*)d_in[5];  // [512, 1]
    const float* b_out    = (const float*)d_in[6];  // [1]
    const int*   src      = (const int*)d_in[7];    // [160000]
    const int*   dst      = (const int*)d_in[8];    // [160000]
    float* out = (float*)d_out;

    // workspace layout
    char* p = (char*)d_ws;
    auto alloc = [&](size_t bytes) {
        char* r = p;
        p += (bytes + 255) & ~size_t(255);
        return r;
    };
    float* x    = (float*)alloc((size_t)N_NODES * DVAL * 4);
    float* agg  = (float*)alloc((size_t)N_NODES * DVAL * 4);
    float* agg6 = (float*)alloc((size_t)N_NODES * 6 * 4);
    int* deg     = (int*)alloc((size_t)N_NODES * 4);
    int* row_ptr = (int*)alloc((size_t)(N_NODES + 1) * 4);
    int* cursor  = (int*)alloc((size_t)N_NODES * 4);
    int* esrc    = (int*)alloc((size_t)N_EDGES * 4);

    // CSR build
    zero_int_kernel<<<(N_NODES + 255) / 256, 256, 0, stream>>>(deg, N_NODES);
    count_deg_kernel<<<(N_EDGES + 255) / 256, 256, 0, stream>>>(dst, deg, N_EDGES);
    scan_kernel<<<1, 1024, 0, stream>>>(deg, row_ptr, cursor);
    fill_edges_kernel<<<(N_EDGES + 255) / 256, 256, 0, stream>>>(src, dst, cursor, esrc, N_EDGES);

    // input layer
    aggregate6_kernel<<<N_NODES, 64, 0, stream>>>(features, row_ptr, esrc, agg6);
    input_layer_kernel<<<N_NODES, 256, 0, stream>>>(agg6, W_in, b_in, x);

    // hidden layers
    dim3 ggrid((N_NODES + BM - 1) / BM, 512 / BN);
    for (int l = 0; l < DEPTH; l++) {
        aggregate512_kernel<<<N_NODES, 128, 0, stream>>>(x, row_ptr, esrc, agg);
        gemm_bias_kernel<<<ggrid, 256, 0, stream>>>(agg, Ws + (size_t)l * 512 * 512,
                                                    bs + (size_t)l * 512, x, N_NODES);
    }

    // output layer
    output_layer_kernel<<<(N_NODES + 3) / 4, 256, 0, stream>>>(x, W_out, b_out, out);
}

// Round 3
// 939.080 us; speedup vs baseline: 1.4922x; 1.4922x over previous
//
#include <hip/hip_runtime.h>

#define N_NODES 10000
#define N_EDGES 160000
#define DVAL    512
#define DEPTH   10

typedef __attribute__((ext_vector_type(8))) short short8;
typedef __attribute__((ext_vector_type(4))) float f32x4;
typedef __attribute__((ext_vector_type(4))) unsigned short u16x4;
typedef __attribute__((ext_vector_type(8))) unsigned short u16x8;

static __device__ inline unsigned short f2bf(float f) {
    unsigned u = __float_as_uint(f);
    unsigned r = (u + 0x7FFF + ((u >> 16) & 1)) >> 16;  // round-to-nearest-even
    return (unsigned short)r;
}
static __device__ inline float bf2f(unsigned short h) {
    return __uint_as_float(((unsigned)h) << 16);
}

// ---------------- CSR build ----------------

__global__ void zero_int_kernel(int* p, int n) {
    int i = blockIdx.x * 256 + threadIdx.x;
    if (i < n) p[i] = 0;
}

__global__ void count_deg_kernel(const int* __restrict__ dst, int* __restrict__ deg, int n) {
    int i = blockIdx.x * 256 + threadIdx.x;
    if (i < n) atomicAdd(&deg[dst[i]], 1);
}

__global__ __launch_bounds__(1024) void scan_kernel(const int* __restrict__ deg,
                                                    int* __restrict__ row_ptr,
                                                    int* __restrict__ cursor) {
    __shared__ int sums[1024];
    const int tid = threadIdx.x;
    const int CH = 10;
    int base = tid * CH;
    int local[CH];
    int s = 0;
#pragma unroll
    for (int i = 0; i < CH; i++) {
        int idx = base + i;
        int v = (idx < N_NODES) ? deg[idx] : 0;
        local[i] = s;
        s += v;
    }
    sums[tid] = s;
    __syncthreads();
    for (int off = 1; off < 1024; off <<= 1) {
        int v = (tid >= off) ? sums[tid - off] : 0;
        __syncthreads();
        sums[tid] += v;
        __syncthreads();
    }
    int chunk_base = (tid > 0) ? sums[tid - 1] : 0;
#pragma unroll
    for (int i = 0; i < CH; i++) {
        int idx = base + i;
        if (idx < N_NODES) {
            int v = chunk_base + local[i];
            row_ptr[idx] = v;
            cursor[idx] = v;
        }
    }
    if (tid == 1023) row_ptr[N_NODES] = sums[1023];
}

__global__ void fill_edges_kernel(const int* __restrict__ src, const int* __restrict__ dst,
                                  int* __restrict__ cursor, int* __restrict__ esrc, int n) {
    int i = blockIdx.x * 256 + threadIdx.x;
    if (i < n) {
        int p = atomicAdd(&cursor[dst[i]], 1);
        esrc[p] = src[i];
    }
}

// ---------------- W prep: transpose + split to bf16 hi/lo ----------------
// Ws[l][k][n] fp32  ->  Wt_hi/Wt_lo[l][n][k] bf16
__global__ __launch_bounds__(256) void transpose_split_kernel(const float* __restrict__ Ws,
                                                              unsigned short* __restrict__ Wt_hi,
                                                              unsigned short* __restrict__ Wt_lo) {
    __shared__ float tile[64][65];
    const int l = blockIdx.z;
    const int kb = blockIdx.x * 64;
    const int nb = blockIdx.y * 64;
    const int t = threadIdx.x;
    const size_t base = (size_t)l * 512 * 512;
#pragma unroll
    for (int i = 0; i < 4; i++) {
        int k = (t >> 4) + i * 16;
        int n4 = (t & 15) * 4;
        float4 v = *(const float4*)(Ws + base + (size_t)(kb + k) * 512 + nb + n4);
        tile[k][n4 + 0] = v.x;
        tile[k][n4 + 1] = v.y;
        tile[k][n4 + 2] = v.z;
        tile[k][n4 + 3] = v.w;
    }
    __syncthreads();
#pragma unroll
    for (int i = 0; i < 4; i++) {
        int n = (t >> 4) + i * 16;
        int k4 = (t & 15) * 4;
        u16x4 h, lo;
#pragma unroll
        for (int j = 0; j < 4; j++) {
            float v = tile[k4 + j][n];
            unsigned short hb = f2bf(v);
            h[j] = hb;
            lo[j] = f2bf(v - bf2f(hb));
        }
        size_t o = base + (size_t)(nb + n) * 512 + kb + k4;
        *(u16x4*)(Wt_hi + o) = h;
        *(u16x4*)(Wt_lo + o) = lo;
    }
}

// ---------------- layer kernels ----------------

__global__ __launch_bounds__(64) void aggregate6_kernel(const float* __restrict__ feat,
                                                        const int* __restrict__ row_ptr,
                                                        const int* __restrict__ esrc,
                                                        float* __restrict__ agg6) {
    int node = blockIdx.x;
    int l = threadIdx.x;
    if (l >= 6) return;
    int start = row_ptr[node], end = row_ptr[node + 1];
    float acc = 0.f;
    for (int e = start; e < end; e++) acc += feat[esrc[e] * 6 + l];
    agg6[node * 6 + l] = acc;
}

__global__ __launch_bounds__(256) void input_layer_kernel(const float* __restrict__ agg6,
                                                          const float* __restrict__ W_in,
                                                          const float* __restrict__ b_in,
                                                          float* __restrict__ x) {
    int node = blockIdx.x;
    int j = threadIdx.x;
    float a[6];
#pragma unroll
    for (int k = 0; k < 6; k++) a[k] = agg6[node * 6 + k];
#pragma unroll
    for (int r = 0; r < 2; r++) {
        int jj = j + r * 256;
        float s = b_in[jj];
#pragma unroll
        for (int k = 0; k < 6; k++) s += a[k] * W_in[k * 512 + jj];
        x[(size_t)node * 512 + jj] = fmaxf(s, 0.f);
    }
}

// chunked aggregation: task = (chunk, node); 64 cols per task; chunk-major for L2 locality
__global__ __launch_bounds__(256) void aggregate512_chunked_kernel(const float* __restrict__ x,
                                                                   const int* __restrict__ row_ptr,
                                                                   const int* __restrict__ esrc,
                                                                   float* __restrict__ agg) {
    int task = blockIdx.x * 4 + (threadIdx.x >> 6);
    int lane = threadIdx.x & 63;
    int node = task % N_NODES;
    int chunk = task / N_NODES;
    int col = chunk * 64 + lane;
    int start = row_ptr[node], end = row_ptr[node + 1];
    float a0 = 0.f, a1 = 0.f, a2 = 0.f, a3 = 0.f;
    int e = start;
    for (; e + 3 < end; e += 4) {
        int s0 = esrc[e], s1 = esrc[e + 1], s2 = esrc[e + 2], s3 = esrc[e + 3];
        a0 += x[(size_t)s0 * 512 + col];
        a1 += x[(size_t)s1 * 512 + col];
        a2 += x[(size_t)s2 * 512 + col];
        a3 += x[(size_t)s3 * 512 + col];
    }
    for (; e < end; e++) a0 += x[(size_t)esrc[e] * 512 + col];
    agg[(size_t)node * 512 + col] = (a0 + a1) + (a2 + a3);
}

// C[M,512] = A[M,512] @ W + bias via split-bf16 MFMA (3 products: hh + hl + lh)
// A fp32, split on the fly. B pre-split/transposed: Wt[n][k] bf16.
// BM=64, BN=128, BK=32. 256 thr = 4 waves, each computes 32x64.
#define GBM 64
#define GBN 128
#define LDK 40  // LDS row pitch in ushorts (k dim padded 32->40)
__global__ __launch_bounds__(256) void gemm_mfma_kernel(const float* __restrict__ A,
                                                        const unsigned short* __restrict__ Bh,
                                                        const unsigned short* __restrict__ Bl,
                                                        const float* __restrict__ bias,
                                                        float* __restrict__ C, int M) {
    __shared__ unsigned short sAh[GBM * LDK];
    __shared__ unsigned short sAl[GBM * LDK];
    __shared__ unsigned short sBh[GBN * LDK];
    __shared__ unsigned short sBl[GBN * LDK];
    const int bm = blockIdx.x * GBM;
    const int bn = blockIdx.y * GBN;
    const int tid = threadIdx.x;
    const int lane = tid & 63;
    const int wave = tid >> 6;
    const int wm = wave & 1;   // m offset 32*wm
    const int wn = wave >> 1;  // n offset 64*wn
    const int l15 = lane & 15;
    const int quad = lane >> 4;
    const int qk = quad * 8;

    f32x4 acc[2][4];
#pragma unroll
    for (int i = 0; i < 2; i++)
#pragma unroll
        for (int j = 0; j < 4; j++) acc[i][j] = (f32x4)0.f;

    // staging maps
    const int am = tid >> 2;             // 0..63
    const int ak = (tid & 3) * 8;        // 0,8,16,24
    const int bn_r = tid >> 1;           // 0..127
    const int bk = (tid & 1) * 16;       // 0,16

    for (int kb = 0; kb < 512; kb += 32) {
        // ---- stage A (64x32 fp32 -> split bf16) ----
        {
            int row = bm + am;
            float4 v0 = make_float4(0.f, 0.f, 0.f, 0.f), v1 = v0;
            if (row < M) {
                const float* p = A + (size_t)row * 512 + kb + ak;
                v0 = *(const float4*)p;
                v1 = *(const float4*)(p + 4);
            }
            float vv[8] = {v0.x, v0.y, v0.z, v0.w, v1.x, v1.y, v1.z, v1.w};
            u16x8 h, lo;
#pragma unroll
            for (int j = 0; j < 8; j++) {
                unsigned short hb = f2bf(vv[j]);
                h[j] = hb;
                lo[j] = f2bf(vv[j] - bf2f(hb));
            }
            *(u16x8*)&sAh[am * LDK + ak] = h;
            *(u16x8*)&sAl[am * LDK + ak] = lo;
        }
        // ---- stage B (128x32 bf16 pre-split) ----
        {
            size_t o = (size_t)(bn + bn_r) * 512 + kb + bk;
            u16x8 h0 = *(const u16x8*)(Bh + o);
            u16x8 h1 = *(const u16x8*)(Bh + o + 8);
            u16x8 l0 = *(const u16x8*)(Bl + o);
            u16x8 l1 = *(const u16x8*)(Bl + o + 8);
            *(u16x8*)&sBh[bn_r * LDK + bk] = h0;
            *(u16x8*)&sBh[bn_r * LDK + bk + 8] = h1;
            *(u16x8*)&sBl[bn_r * LDK + bk] = l0;
            *(u16x8*)&sBl[bn_r * LDK + bk + 8] = l1;
        }
        __syncthreads();
        // ---- fragments + MFMA ----
        short8 afh[2], afl[2], bfh[4], bfl[4];
#pragma unroll
        for (int mt = 0; mt < 2; mt++) {
            int r = 32 * wm + 16 * mt + l15;
            afh[mt] = *(const short8*)&sAh[r * LDK + qk];
            afl[mt] = *(const short8*)&sAl[r * LDK + qk];
        }
#pragma unroll
        for (int nt = 0; nt < 4; nt++) {
            int r = 64 * wn + 16 * nt + l15;
            bfh[nt] = *(const short8*)&sBh[r * LDK + qk];
            bfl[nt] = *(const short8*)&sBl[r * LDK + qk];
        }
#pragma unroll
        for (int mt = 0; mt < 2; mt++)
#pragma unroll
            for (int nt = 0; nt < 4; nt++) {
                acc[mt][nt] = __builtin_amdgcn_mfma_f32_16x16x32_bf16(afh[mt], bfh[nt], acc[mt][nt], 0, 0, 0);
                acc[mt][nt] = __builtin_amdgcn_mfma_f32_16x16x32_bf16(afh[mt], bfl[nt], acc[mt][nt], 0, 0, 0);
                acc[mt][nt] = __builtin_amdgcn_mfma_f32_16x16x32_bf16(afl[mt], bfh[nt], acc[mt][nt], 0, 0, 0);
            }
        __syncthreads();
    }

    // ---- epilogue: bias + store (C/D: col=lane&15, row=quad*4+reg) ----
#pragma unroll
    for (int nt = 0; nt < 4; nt++) {
        int col = bn + 64 * wn + 16 * nt + l15;
        float bv = bias[col];
#pragma unroll
        for (int mt = 0; mt < 2; mt++) {
#pragma unroll
            for (int r = 0; r < 4; r++) {
                int row = bm + 32 * wm + 16 * mt + quad * 4 + r;
                if (row < M) C[(size_t)row * 512 + col] = acc[mt][nt][r] + bv;
            }
        }
    }
}

__global__ __launch_bounds__(256) void output_layer_kernel(const float* __restrict__ x,
                                                           const float* __restrict__ W_out,
                                                           const float* __restrict__ b_out,
                                                           float* __restrict__ out) {
    int wave = threadIdx.x >> 6;
    int lane = threadIdx.x & 63;
    int node = blockIdx.x * 4 + wave;
    if (node >= N_NODES) return;
    float s = 0.f;
#pragma unroll
    for (int r = 0; r < 8; r++) {
        int k = lane + r * 64;
        s += x[(size_t)node * 512 + k] * W_out[k];
    }
#pragma unroll
    for (int off = 32; off > 0; off >>= 1) s += __shfl_down(s, off, 64);
    if (lane == 0) out[node] = s + b_out[0];
}

// ---------------- launch ----------------

extern "C" void kernel_launch(void* const* d_in, const int* in_sizes, int n_in,
                              void* d_out, int out_size, void* d_ws, size_t ws_size,
                              hipStream_t stream) {
    const float* features = (const float*)d_in[0];
    const float* W_in     = (const float*)d_in[1];
    const float* b_in     = (const float*)d_in[2];
    const float* Ws       = (const float*)d_in[3];
    const float* bs       = (const float*)d_in[4];
    const float* W_out    = (const float*)d_in[5];
    const float* b_out    = (const float*)d_in[6];
    const int*   src      = (const int*)d_in[7];
    const int*   dst      = (const int*)d_in[8];
    float* out = (float*)d_out;

    char* p = (char*)d_ws;
    auto alloc = [&](size_t bytes) {
        char* r = p;
        p += (bytes + 255) & ~size_t(255);
        return r;
    };
    float* x    = (float*)alloc((size_t)N_NODES * DVAL * 4);
    float* agg  = (float*)alloc((size_t)N_NODES * DVAL * 4);
    float* agg6 = (float*)alloc((size_t)N_NODES * 6 * 4);
    int* deg     = (int*)alloc((size_t)N_NODES * 4);
    int* row_ptr = (int*)alloc((size_t)(N_NODES + 1) * 4);
    int* cursor  = (int*)alloc((size_t)N_NODES * 4);
    int* esrc    = (int*)alloc((size_t)N_EDGES * 4);
    unsigned short* Wt_hi = (unsigned short*)alloc((size_t)DEPTH * 512 * 512 * 2);
    unsigned short* Wt_lo = (unsigned short*)alloc((size_t)DEPTH * 512 * 512 * 2);

    // CSR build
    zero_int_kernel<<<(N_NODES + 255) / 256, 256, 0, stream>>>(deg, N_NODES);
    count_deg_kernel<<<(N_EDGES + 255) / 256, 256, 0, stream>>>(dst, deg, N_EDGES);
    scan_kernel<<<1, 1024, 0, stream>>>(deg, row_ptr, cursor);
    fill_edges_kernel<<<(N_EDGES + 255) / 256, 256, 0, stream>>>(src, dst, cursor, esrc, N_EDGES);

    // W prep (once per call)
    transpose_split_kernel<<<dim3(8, 8, DEPTH), 256, 0, stream>>>(Ws, Wt_hi, Wt_lo);

    // input layer
    aggregate6_kernel<<<N_NODES, 64, 0, stream>>>(features, row_ptr, esrc, agg6);
    input_layer_kernel<<<N_NODES, 256, 0, stream>>>(agg6, W_in, b_in, x);

    // hidden layers
    dim3 ggrid((N_NODES + GBM - 1) / GBM, 512 / GBN);
    const int agg_blocks = (N_NODES * 8) / 4;  // 8 chunks of 64 cols, 4 tasks/block
    for (int l = 0; l < DEPTH; l++) {
        aggregate512_chunked_kernel<<<agg_blocks, 256, 0, stream>>>(x, row_ptr, esrc, agg);
        gemm_mfma_kernel<<<ggrid, 256, 0, stream>>>(agg,
                                                    Wt_hi + (size_t)l * 512 * 512,
                                                    Wt_lo + (size_t)l * 512 * 512,
                                                    bs + (size_t)l * 512, x, N_NODES);
    }

    // output layer
    output_layer_kernel<<<(N_NODES + 3) / 4, 256, 0, stream>>>(x, W_out, b_out, out);
}

// Round 4
// 841.673 us; speedup vs baseline: 1.6649x; 1.1157x over previous
//
#include <hip/hip_runtime.h>

#define N_NODES 10000
#define N_EDGES 160000
#define DVAL    512
#define DEPTH   10

typedef __attribute__((ext_vector_type(8))) short short8;
typedef __attribute__((ext_vector_type(4))) float f32x4;
typedef __attribute__((ext_vector_type(4))) unsigned short u16x4;
typedef __attribute__((ext_vector_type(8))) unsigned short u16x8;

static __device__ inline unsigned short f2bf(float f) {
    unsigned u = __float_as_uint(f);
    unsigned r = (u + 0x7FFF + ((u >> 16) & 1)) >> 16;  // round-to-nearest-even
    return (unsigned short)r;
}
static __device__ inline float bf2f(unsigned short h) {
    return __uint_as_float(((unsigned)h) << 16);
}

// ---------------- CSR build ----------------

__global__ void zero_int_kernel(int* p, int n) {
    int i = blockIdx.x * 256 + threadIdx.x;
    if (i < n) p[i] = 0;
}

__global__ void count_deg_kernel(const int* __restrict__ dst, int* __restrict__ deg, int n) {
    int i = blockIdx.x * 256 + threadIdx.x;
    if (i < n) atomicAdd(&deg[dst[i]], 1);
}

__global__ __launch_bounds__(1024) void scan_kernel(const int* __restrict__ deg,
                                                    int* __restrict__ row_ptr,
                                                    int* __restrict__ cursor) {
    __shared__ int sums[1024];
    const int tid = threadIdx.x;
    const int CH = 10;
    int base = tid * CH;
    int local[CH];
    int s = 0;
#pragma unroll
    for (int i = 0; i < CH; i++) {
        int idx = base + i;
        int v = (idx < N_NODES) ? deg[idx] : 0;
        local[i] = s;
        s += v;
    }
    sums[tid] = s;
    __syncthreads();
    for (int off = 1; off < 1024; off <<= 1) {
        int v = (tid >= off) ? sums[tid - off] : 0;
        __syncthreads();
        sums[tid] += v;
        __syncthreads();
    }
    int chunk_base = (tid > 0) ? sums[tid - 1] : 0;
#pragma unroll
    for (int i = 0; i < CH; i++) {
        int idx = base + i;
        if (idx < N_NODES) {
            int v = chunk_base + local[i];
            row_ptr[idx] = v;
            cursor[idx] = v;
        }
    }
    if (tid == 1023) row_ptr[N_NODES] = sums[1023];
}

__global__ void fill_edges_kernel(const int* __restrict__ src, const int* __restrict__ dst,
                                  int* __restrict__ cursor, int* __restrict__ esrc, int n) {
    int i = blockIdx.x * 256 + threadIdx.x;
    if (i < n) {
        int p = atomicAdd(&cursor[dst[i]], 1);
        esrc[p] = src[i];
    }
}

// ---------------- W prep: transpose + split to bf16 hi/lo ----------------
// Ws[l][k][n] fp32  ->  Wt_hi/Wt_lo[l][n][k] bf16
__global__ __launch_bounds__(256) void transpose_split_kernel(const float* __restrict__ Ws,
                                                              unsigned short* __restrict__ Wt_hi,
                                                              unsigned short* __restrict__ Wt_lo) {
    __shared__ float tile[64][65];
    const int l = blockIdx.z;
    const int kb = blockIdx.x * 64;
    const int nb = blockIdx.y * 64;
    const int t = threadIdx.x;
    const size_t base = (size_t)l * 512 * 512;
#pragma unroll
    for (int i = 0; i < 4; i++) {
        int k = (t >> 4) + i * 16;
        int n4 = (t & 15) * 4;
        float4 v = *(const float4*)(Ws + base + (size_t)(kb + k) * 512 + nb + n4);
        tile[k][n4 + 0] = v.x;
        tile[k][n4 + 1] = v.y;
        tile[k][n4 + 2] = v.z;
        tile[k][n4 + 3] = v.w;
    }
    __syncthreads();
#pragma unroll
    for (int i = 0; i < 4; i++) {
        int n = (t >> 4) + i * 16;
        int k4 = (t & 15) * 4;
        u16x4 h, lo;
#pragma unroll
        for (int j = 0; j < 4; j++) {
            float v = tile[k4 + j][n];
            unsigned short hb = f2bf(v);
            h[j] = hb;
            lo[j] = f2bf(v - bf2f(hb));
        }
        size_t o = base + (size_t)(nb + n) * 512 + kb + k4;
        *(u16x4*)(Wt_hi + o) = h;
        *(u16x4*)(Wt_lo + o) = lo;
    }
}

// ---------------- layer kernels ----------------

__global__ __launch_bounds__(64) void aggregate6_kernel(const float* __restrict__ feat,
                                                        const int* __restrict__ row_ptr,
                                                        const int* __restrict__ esrc,
                                                        float* __restrict__ agg6) {
    int node = blockIdx.x;
    int l = threadIdx.x;
    if (l >= 6) return;
    int start = row_ptr[node], end = row_ptr[node + 1];
    float acc = 0.f;
    for (int e = start; e < end; e++) acc += feat[esrc[e] * 6 + l];
    agg6[node * 6 + l] = acc;
}

__global__ __launch_bounds__(256) void input_layer_kernel(const float* __restrict__ agg6,
                                                          const float* __restrict__ W_in,
                                                          const float* __restrict__ b_in,
                                                          float* __restrict__ x) {
    int node = blockIdx.x;
    int j = threadIdx.x;
    float a[6];
#pragma unroll
    for (int k = 0; k < 6; k++) a[k] = agg6[node * 6 + k];
#pragma unroll
    for (int r = 0; r < 2; r++) {
        int jj = j + r * 256;
        float s = b_in[jj];
#pragma unroll
        for (int k = 0; k < 6; k++) s += a[k] * W_in[k * 512 + jj];
        x[(size_t)node * 512 + jj] = fmaxf(s, 0.f);
    }
}

// XCD-pinned chunked aggregation + bf16 hi/lo split epilogue.
// chunk = blockIdx & 7: with round-robin block->XCD dispatch, each XCD's L2
// serves exactly one 64-col slice of x (2.56 MB < 4 MB per-XCD L2).
__global__ __launch_bounds__(256) void aggregate_split_kernel(const float* __restrict__ x,
                                                              const int* __restrict__ row_ptr,
                                                              const int* __restrict__ esrc,
                                                              unsigned short* __restrict__ agg_hi,
                                                              unsigned short* __restrict__ agg_lo) {
    const int b = blockIdx.x;
    const int chunk = b & 7;
    const int w = threadIdx.x >> 6;
    const int lane = threadIdx.x & 63;
    const int node = (b >> 3) * 4 + w;
    const int col = chunk * 64 + lane;
    const int start = row_ptr[node], end = row_ptr[node + 1];
    float a0 = 0.f, a1 = 0.f, a2 = 0.f, a3 = 0.f, a4 = 0.f, a5 = 0.f, a6 = 0.f, a7 = 0.f;
    int e = start;
    for (; e + 8 <= end; e += 8) {
        int s0 = esrc[e + 0], s1 = esrc[e + 1], s2 = esrc[e + 2], s3 = esrc[e + 3];
        int s4 = esrc[e + 4], s5 = esrc[e + 5], s6 = esrc[e + 6], s7 = esrc[e + 7];
        a0 += x[(size_t)s0 * 512 + col];
        a1 += x[(size_t)s1 * 512 + col];
        a2 += x[(size_t)s2 * 512 + col];
        a3 += x[(size_t)s3 * 512 + col];
        a4 += x[(size_t)s4 * 512 + col];
        a5 += x[(size_t)s5 * 512 + col];
        a6 += x[(size_t)s6 * 512 + col];
        a7 += x[(size_t)s7 * 512 + col];
    }
    for (; e < end; e++) a0 += x[(size_t)esrc[e] * 512 + col];
    float s = ((a0 + a1) + (a2 + a3)) + ((a4 + a5) + (a6 + a7));
    unsigned short hb = f2bf(s);
    size_t o = (size_t)node * 512 + col;
    agg_hi[o] = hb;
    agg_lo[o] = f2bf(s - bf2f(hb));
}

// C[M,512] = A @ W + bias via split-bf16 MFMA (3 products: hh + hl + lh).
// A pre-split by aggregation (Ah/Al bf16 [m][k]); B pre-split/transposed Wt[n][k].
// BM=64, BN=128, BK=32. 256 thr = 4 waves, each computes 32x64.
#define GBM 64
#define GBN 128
#define LDK 40  // LDS row pitch in ushorts (k dim padded 32->40)
__global__ __launch_bounds__(256) void gemm_mfma_kernel(const unsigned short* __restrict__ Ah,
                                                        const unsigned short* __restrict__ Al,
                                                        const unsigned short* __restrict__ Bh,
                                                        const unsigned short* __restrict__ Bl,
                                                        const float* __restrict__ bias,
                                                        float* __restrict__ C, int M) {
    __shared__ unsigned short sAh[GBM * LDK];
    __shared__ unsigned short sAl[GBM * LDK];
    __shared__ unsigned short sBh[GBN * LDK];
    __shared__ unsigned short sBl[GBN * LDK];
    const int bm = blockIdx.x * GBM;
    const int bn = blockIdx.y * GBN;
    const int tid = threadIdx.x;
    const int lane = tid & 63;
    const int wave = tid >> 6;
    const int wm = wave & 1;   // m offset 32*wm
    const int wn = wave >> 1;  // n offset 64*wn
    const int l15 = lane & 15;
    const int quad = lane >> 4;
    const int qk = quad * 8;

    f32x4 acc[2][4];
#pragma unroll
    for (int i = 0; i < 2; i++)
#pragma unroll
        for (int j = 0; j < 4; j++) acc[i][j] = (f32x4)0.f;

    // staging maps
    const int am = tid >> 2;             // 0..63
    const int ak = (tid & 3) * 8;        // 0,8,16,24
    const int bn_r = tid >> 1;           // 0..127
    const int bk = (tid & 1) * 16;       // 0,16

    for (int kb = 0; kb < 512; kb += 32) {
        // ---- stage A (64x32, pre-split bf16) ----
        {
            int row = bm + am;
            u16x8 h = {0, 0, 0, 0, 0, 0, 0, 0};
            u16x8 lo = {0, 0, 0, 0, 0, 0, 0, 0};
            if (row < M) {
                size_t o = (size_t)row * 512 + kb + ak;
                h = *(const u16x8*)(Ah + o);
                lo = *(const u16x8*)(Al + o);
            }
            *(u16x8*)&sAh[am * LDK + ak] = h;
            *(u16x8*)&sAl[am * LDK + ak] = lo;
        }
        // ---- stage B (128x32, pre-split bf16) ----
        {
            size_t o = (size_t)(bn + bn_r) * 512 + kb + bk;
            u16x8 h0 = *(const u16x8*)(Bh + o);
            u16x8 h1 = *(const u16x8*)(Bh + o + 8);
            u16x8 l0 = *(const u16x8*)(Bl + o);
            u16x8 l1 = *(const u16x8*)(Bl + o + 8);
            *(u16x8*)&sBh[bn_r * LDK + bk] = h0;
            *(u16x8*)&sBh[bn_r * LDK + bk + 8] = h1;
            *(u16x8*)&sBl[bn_r * LDK + bk] = l0;
            *(u16x8*)&sBl[bn_r * LDK + bk + 8] = l1;
        }
        __syncthreads();
        // ---- fragments + MFMA ----
        short8 afh[2], afl[2], bfh[4], bfl[4];
#pragma unroll
        for (int mt = 0; mt < 2; mt++) {
            int r = 32 * wm + 16 * mt + l15;
            afh[mt] = *(const short8*)&sAh[r * LDK + qk];
            afl[mt] = *(const short8*)&sAl[r * LDK + qk];
        }
#pragma unroll
        for (int nt = 0; nt < 4; nt++) {
            int r = 64 * wn + 16 * nt + l15;
            bfh[nt] = *(const short8*)&sBh[r * LDK + qk];
            bfl[nt] = *(const short8*)&sBl[r * LDK + qk];
        }
#pragma unroll
        for (int mt = 0; mt < 2; mt++)
#pragma unroll
            for (int nt = 0; nt < 4; nt++) {
                acc[mt][nt] = __builtin_amdgcn_mfma_f32_16x16x32_bf16(afh[mt], bfh[nt], acc[mt][nt], 0, 0, 0);
                acc[mt][nt] = __builtin_amdgcn_mfma_f32_16x16x32_bf16(afh[mt], bfl[nt], acc[mt][nt], 0, 0, 0);
                acc[mt][nt] = __builtin_amdgcn_mfma_f32_16x16x32_bf16(afl[mt], bfh[nt], acc[mt][nt], 0, 0, 0);
            }
        __syncthreads();
    }

    // ---- epilogue: bias + store (C/D: col=lane&15, row=quad*4+reg) ----
#pragma unroll
    for (int nt = 0; nt < 4; nt++) {
        int col = bn + 64 * wn + 16 * nt + l15;
        float bv = bias[col];
#pragma unroll
        for (int mt = 0; mt < 2; mt++) {
#pragma unroll
            for (int r = 0; r < 4; r++) {
                int row = bm + 32 * wm + 16 * mt + quad * 4 + r;
                if (row < M) C[(size_t)row * 512 + col] = acc[mt][nt][r] + bv;
            }
        }
    }
}

__global__ __launch_bounds__(256) void output_layer_kernel(const float* __restrict__ x,
                                                           const float* __restrict__ W_out,
                                                           const float* __restrict__ b_out,
                                                           float* __restrict__ out) {
    int wave = threadIdx.x >> 6;
    int lane = threadIdx.x & 63;
    int node = blockIdx.x * 4 + wave;
    if (node >= N_NODES) return;
    float s = 0.f;
#pragma unroll
    for (int r = 0; r < 8; r++) {
        int k = lane + r * 64;
        s += x[(size_t)node * 512 + k] * W_out[k];
    }
#pragma unroll
    for (int off = 32; off > 0; off >>= 1) s += __shfl_down(s, off, 64);
    if (lane == 0) out[node] = s + b_out[0];
}

// ---------------- launch ----------------

extern "C" void kernel_launch(void* const* d_in, const int* in_sizes, int n_in,
                              void* d_out, int out_size, void* d_ws, size_t ws_size,
                              hipStream_t stream) {
    const float* features = (const float*)d_in[0];
    const float* W_in     = (const float*)d_in[1];
    const float* b_in     = (const float*)d_in[2];
    const float* Ws       = (const float*)d_in[3];
    const float* bs       = (const float*)d_in[4];
    const float* W_out    = (const float*)d_in[5];
    const float* b_out    = (const float*)d_in[6];
    const int*   src      = (const int*)d_in[7];
    const int*   dst      = (const int*)d_in[8];
    float* out = (float*)d_out;

    char* p = (char*)d_ws;
    auto alloc = [&](size_t bytes) {
        char* r = p;
        p += (bytes + 255) & ~size_t(255);
        return r;
    };
    float* x    = (float*)alloc((size_t)N_NODES * DVAL * 4);
    unsigned short* agg_hi = (unsigned short*)alloc((size_t)N_NODES * DVAL * 2);
    unsigned short* agg_lo = (unsigned short*)alloc((size_t)N_NODES * DVAL * 2);
    float* agg6 = (float*)alloc((size_t)N_NODES * 6 * 4);
    int* deg     = (int*)alloc((size_t)N_NODES * 4);
    int* row_ptr = (int*)alloc((size_t)(N_NODES + 1) * 4);
    int* cursor  = (int*)alloc((size_t)N_NODES * 4);
    int* esrc    = (int*)alloc((size_t)N_EDGES * 4);
    unsigned short* Wt_hi = (unsigned short*)alloc((size_t)DEPTH * 512 * 512 * 2);
    unsigned short* Wt_lo = (unsigned short*)alloc((size_t)DEPTH * 512 * 512 * 2);

    // CSR build
    zero_int_kernel<<<(N_NODES + 255) / 256, 256, 0, stream>>>(deg, N_NODES);
    count_deg_kernel<<<(N_EDGES + 255) / 256, 256, 0, stream>>>(dst, deg, N_EDGES);
    scan_kernel<<<1, 1024, 0, stream>>>(deg, row_ptr, cursor);
    fill_edges_kernel<<<(N_EDGES + 255) / 256, 256, 0, stream>>>(src, dst, cursor, esrc, N_EDGES);

    // W prep (once per call)
    transpose_split_kernel<<<dim3(8, 8, DEPTH), 256, 0, stream>>>(Ws, Wt_hi, Wt_lo);

    // input layer
    aggregate6_kernel<<<N_NODES, 64, 0, stream>>>(features, row_ptr, esrc, agg6);
    input_layer_kernel<<<N_NODES, 256, 0, stream>>>(agg6, W_in, b_in, x);

    // hidden layers
    dim3 ggrid((N_NODES + GBM - 1) / GBM, 512 / GBN);
    const int agg_blocks = 2500 * 8;  // (node groups of 4 waves) x 8 chunks
    for (int l = 0; l < DEPTH; l++) {
        aggregate_split_kernel<<<agg_blocks, 256, 0, stream>>>(x, row_ptr, esrc, agg_hi, agg_lo);
        gemm_mfma_kernel<<<ggrid, 256, 0, stream>>>(agg_hi, agg_lo,
                                                    Wt_hi + (size_t)l * 512 * 512,
                                                    Wt_lo + (size_t)l * 512 * 512,
                                                    bs + (size_t)l * 512, x, N_NODES);
    }

    // output layer
    output_layer_kernel<<<(N_NODES + 3) / 4, 256, 0, stream>>>(x, W_out, b_out, out);
}